// Round 6
// baseline (96.605 us; speedup 1.0000x reference)
//
#include <hip/hip_runtime.h>
#include <hip/hip_bf16.h>
#include <math.h>

// MultiBoxLoss: B=64, P=16800, G=32, C=2. Atomic-free (global) 4-kernel pipeline.
// k_gt     : transposed per-gt best-prior argmax -> keys.
// k_match  : wave-AABB gt pruning; threshold test w/o division for negatives;
//            forced-match via LDS scatter; argmax only on rare positive lanes.
// k_select : per-batch partial reduce + exact k-th largest via bit bisection.
// k_final  : 64 rows -> 3 scalars.

#define RCP(x) __builtin_amdgcn_rcpf(x)

constexpr int GN = 32;

__device__ __forceinline__ float sl1(float x) {
    float a = fabsf(x);
    return a < 1.f ? 0.5f * a * a : a - 0.5f;
}

// ---- k_gt: per-gt best prior (max iou, ties -> smallest p) ----
constexpr int GPB = 4;
constexpr int GNT = 512;
__global__ __launch_bounds__(GNT)
void k_gt(const float4* __restrict__ priors, const float* __restrict__ targets,
          unsigned long long* __restrict__ keys, int P, int G) {
    const int b = blockIdx.y, g0 = blockIdx.x * GPB, tid = threadIdx.x;
    const int lane = tid & 63, w = tid >> 6;
    __shared__ float4 s_box[GPB];
    __shared__ float  s_at[GPB];
    __shared__ unsigned long long s_wk[GNT / 64][GPB];
    if (tid < GPB) {
        const float* t = targets + ((size_t)b * G + g0 + tid) * 15;
        float4 v = make_float4(t[0], t[1], t[2], t[3]);
        s_box[tid] = v;
        s_at[tid] = (v.z - v.x) * (v.w - v.y);
    }
    __syncthreads();
    float4 tb0 = s_box[0], tb1 = s_box[1], tb2 = s_box[2], tb3 = s_box[3];
    float at0 = s_at[0], at1 = s_at[1], at2 = s_at[2], at3 = s_at[3];

    float bv[GPB]; int bp[GPB];
    #pragma unroll
    for (int j = 0; j < GPB; ++j) { bv[j] = -1.f; bp[j] = 0; }

    for (int p = tid; p < P; p += GNT) {     // ascending p: '>' keeps smallest p
        float4 pr = priors[p];
        float hx = pr.z * 0.5f, hy = pr.w * 0.5f;
        float px0 = pr.x - hx, py0 = pr.y - hy;
        float px1 = pr.x + hx, py1 = pr.y + hy;
        float ap = (px1 - px0) * (py1 - py0);
        #pragma unroll
        for (int j = 0; j < GPB; ++j) {
            float4 tb = j == 0 ? tb0 : (j == 1 ? tb1 : (j == 2 ? tb2 : tb3));
            float at = j == 0 ? at0 : (j == 1 ? at1 : (j == 2 ? at2 : at3));
            float lx = fmaxf(tb.x, px0), ly = fmaxf(tb.y, py0);
            float rx = fminf(tb.z, px1), ry = fminf(tb.w, py1);
            float iw = fmaxf(rx - lx, 0.f), ih = fmaxf(ry - ly, 0.f);
            float inter = iw * ih;
            float iou = inter * RCP(at + ap - inter);
            if (iou > bv[j]) { bv[j] = iou; bp[j] = p; }
        }
    }
    #pragma unroll
    for (int j = 0; j < GPB; ++j) {
        unsigned long long key =
            ((unsigned long long)__float_as_uint(bv[j]) << 32) | ~(unsigned)bp[j];
        #pragma unroll
        for (int o = 32; o > 0; o >>= 1) {
            unsigned long long t = __shfl_down(key, o, 64);
            if (t > key) key = t;
        }
        if (lane == 0) s_wk[w][j] = key;
    }
    __syncthreads();
    if (tid < GPB) {
        unsigned long long m = 0ull;
        #pragma unroll
        for (int q = 0; q < GNT / 64; ++q) { unsigned long long t = s_wk[q][tid]; if (t > m) m = t; }
        keys[b * G + g0 + tid] = m;
    }
}

// ---- k_match ----
__global__ __launch_bounds__(256)
void k_match(const float2* __restrict__ cls, const float4* __restrict__ loc,
             const float* __restrict__ lmd, const float4* __restrict__ priors,
             const float* __restrict__ targets,
             const unsigned long long* __restrict__ keys,
             float* __restrict__ bc, float* __restrict__ part, int P, int NB) {
    const int b = blockIdx.y, bx = blockIdx.x, tid = threadIdx.x;
    const int lane = tid & 63, w = tid >> 6;
    __shared__ float4 s_box[GN];                 // gt corner boxes
    __shared__ float  s_at[GN];                  // areas (rare path)
    __shared__ float  s_c035[GN];                // 0.35 * area
    __shared__ float  s_lm[GN * 10];
    __shared__ float  s_lab[GN];
    __shared__ int    s_fg[256];                 // forced: max g per local prior
    __shared__ int    s_fv[256];                 // forced: any valid g
    __shared__ unsigned s_vm;
    __shared__ float  s_red[4][8];

    s_fg[tid] = -1; s_fv[tid] = 0;
    for (int i = tid; i < GN * 15; i += 256) {
        int g = i / 15, j = i - g * 15;
        float v = targets[((size_t)b * GN + g) * 15 + j];
        if (j < 4) ((float*)&s_box[g])[j] = v;
        else if (j < 14) s_lm[g * 10 + (j - 4)] = v;
        else s_lab[g] = v;
    }
    __syncthreads();
    if (tid < GN) {
        float4 v = s_box[tid];
        float at = (v.z - v.x) * (v.w - v.y);
        s_at[tid] = at;
        s_c035[tid] = 0.35f * at;
        unsigned long long key = keys[b * GN + tid];
        unsigned bp = ~(unsigned)key;                    // best prior idx for gt tid
        bool val = __uint_as_float((unsigned)(key >> 32)) >= 0.2f;
        unsigned long long bal = __ballot(val);          // lanes 0..31 of wave 0
        if (tid == 0) s_vm = (unsigned)bal;
        int local = (int)bp - bx * 256;
        if (local >= 0 && local < 256) {
            atomicMax(&s_fg[local], tid);                // largest g wins
            if (val) atomicOr(&s_fv[local], 1);          // any valid g
        }
    }
    __syncthreads();
    const bool av = s_vm != 0u;
    const int  fidx = s_fg[tid];
    const bool fv = s_fv[tid] != 0;

    int p = bx * 256 + tid;
    const bool act = p < P;
    float4 pr = act ? priors[p] : make_float4(0.f, 0.f, 0.f, 0.f);
    float hx = pr.z * 0.5f, hy = pr.w * 0.5f;
    float px0 = pr.x - hx, py0 = pr.y - hy;
    float px1 = pr.x + hx, py1 = pr.y + hy;
    float ap = (px1 - px0) * (py1 - py0);
    if (!act) { px0 = py0 = INFINITY; px1 = py1 = -INFINITY; }

    // wave AABB of this wave's priors
    float wx0 = px0, wy0 = py0, wx1 = px1, wy1 = py1;
    #pragma unroll
    for (int o = 32; o > 0; o >>= 1) {
        wx0 = fminf(wx0, __shfl_xor(wx0, o, 64));
        wy0 = fminf(wy0, __shfl_xor(wy0, o, 64));
        wx1 = fmaxf(wx1, __shfl_xor(wx1, o, 64));
        wy1 = fmaxf(wy1, __shfl_xor(wy1, o, 64));
    }
    // gt-survival mask (gt g can have nonzero intersection with some lane)
    bool sg = false;
    if (lane < GN) {
        float4 tb = s_box[lane];
        sg = (tb.x < wx1) && (tb.z > wx0) && (tb.y < wy1) && (tb.w > wy0);
    }
    unsigned mask = (unsigned)__ballot(sg);

    // threshold pass (no division): iou>=0.35 <=> 1.35*inter - 0.35*at >= 0.35*ap
    float qmax = -INFINITY;
    unsigned m2 = mask;
    while (m2) {
        int g = __ffs(m2) - 1; m2 &= m2 - 1;
        float4 tb = s_box[g];
        float lx = fmaxf(tb.x, px0), ly = fmaxf(tb.y, py0);
        float rx = fminf(tb.z, px1), ry = fminf(tb.w, py1);
        float iw = fmaxf(rx - lx, 0.f), ih = fmaxf(ry - ly, 0.f);
        float inter = iw * ih;
        qmax = fmaxf(qmax, fmaf(1.35f, inter, -s_c035[g]));
    }
    bool thr = act && (qmax >= 0.35f * ap);
    bool pos = act && av && (fv || thr);

    float lse = 0.f, d = 0.f;
    if (act) {
        float2 c = cls[(size_t)b * P + p];
        d = c.y - c.x;
        float m0 = fmaxf(d, 0.f);
        lse = m0 + __logf(__expf(-m0) + __expf(d - m0));   // logz - c.x >= 0
        bc[(size_t)b * P + p] = pos ? 0.f : lse;
    }

    float a_ll = 0.f, a_lm = 0.f, a_lcp = 0.f;
    bool posl = false;
    if (pos) {
        a_lcp = lse - d;                                   // logz - c.y
        int bti2 = fidx;
        if (fidx < 0) {                                    // rare: full argmax
            float btv = -1.f;
            unsigned m3 = mask;
            while (m3) {
                int g = __ffs(m3) - 1; m3 &= m3 - 1;
                float4 tb = s_box[g];
                float lx = fmaxf(tb.x, px0), ly = fmaxf(tb.y, py0);
                float rx = fminf(tb.z, px1), ry = fminf(tb.w, py1);
                float iw = fmaxf(rx - lx, 0.f), ih = fmaxf(ry - ly, 0.f);
                float inter = iw * ih;
                float iou = inter * RCP(s_at[g] + ap - inter);
                if (iou > btv) { btv = iou; bti2 = g; }    // first-g argmax
            }
        }
        float4 tb = s_box[bti2];
        float rw = RCP(pr.z), rh = RCP(pr.w);
        float e0 = ((tb.x + tb.z) * 0.5f - pr.x) * rw * 10.f;
        float e1 = ((tb.y + tb.w) * 0.5f - pr.y) * rh * 10.f;
        float e2 = __logf((tb.z - tb.x) * rw) * 5.f;
        float e3 = __logf((tb.w - tb.y) * rh) * 5.f;
        float4 ld = loc[(size_t)b * P + p];
        a_ll = sl1(ld.x - e0) + sl1(ld.y - e1) + sl1(ld.z - e2) + sl1(ld.w - e3);
        if (s_lab[bti2] > 0.f) {                           // conf > 0
            posl = true;
            const float* lp = lmd + ((size_t)b * P + p) * 10;
            #pragma unroll
            for (int q = 0; q < 5; ++q) {
                float gx = (s_lm[bti2 * 10 + 2 * q]     - pr.x) * rw * 10.f;
                float gy = (s_lm[bti2 * 10 + 2 * q + 1] - pr.y) * rh * 10.f;
                a_lm += sl1(lp[2 * q] - gx) + sl1(lp[2 * q + 1] - gy);
            }
        }
    }

    // per-wave reduce: counts via ballot; float sums only if wave has positives
    unsigned long long bpos = __ballot(pos);
    int npw  = __popcll(bpos);
    int np1w = __popcll(__ballot(posl));
    if (bpos) {
        #pragma unroll
        for (int o = 32; o > 0; o >>= 1) {
            a_ll  += __shfl_down(a_ll,  o, 64);
            a_lm  += __shfl_down(a_lm,  o, 64);
            a_lcp += __shfl_down(a_lcp, o, 64);
        }
    }
    if (lane == 0) {
        s_red[w][0] = a_ll; s_red[w][1] = a_lm; s_red[w][2] = a_lcp;
        s_red[w][3] = (float)npw; s_red[w][4] = (float)np1w;
    }
    __syncthreads();
    if (tid == 0) {
        float* pp = part + ((size_t)b * NB + bx) * 8;
        #pragma unroll
        for (int j = 0; j < 5; ++j)
            pp[j] = s_red[0][j] + s_red[1][j] + s_red[2][j] + s_red[3][j];
    }
}

// ---- k_select: per-batch reduce + exact top-k sum via bit bisection ----
constexpr int SNT = 1024;
constexpr int SNI = 17;
__global__ __launch_bounds__(SNT)
void k_select(const float* __restrict__ bc, const float* __restrict__ part,
              float* __restrict__ part2, int P, int NB) {
    const int b = blockIdx.x, tid = threadIdx.x;
    const int lane = tid & 63, w = tid >> 6;
    unsigned ul[SNI];
    #pragma unroll
    for (int i = 0; i < SNI; ++i) {
        int idx = i * SNT + tid;
        ul[i] = idx < P ? __float_as_uint(bc[(size_t)b * P + idx]) : 0u;
    }
    __shared__ float s_r[5];
    if (w < 5) {
        float s = 0.f;
        for (int bx = lane; bx < NB; bx += 64) s += part[((size_t)b * NB + bx) * 8 + w];
        #pragma unroll
        for (int o = 32; o > 0; o >>= 1) s += __shfl_down(s, o, 64);
        if (lane == 0) s_r[w] = s;
    }
    __syncthreads();
    float t_ll = s_r[0], t_lm = s_r[1], t_lcp = s_r[2], t_np = s_r[3], t_np1 = s_r[4];
    int np = (int)(t_np + 0.5f);
    int k = np * 7;
    if (k > P - 1) k = P - 1;

    __shared__ int s_ri[16];
    __shared__ int s_i0;
    __shared__ float s_rf[16];
    float topk = 0.f;
    if (k > 0) {
        unsigned lo = 0u, hi = 0x7f800000u;
        while (lo < hi) {
            unsigned mid = lo + ((hi - lo + 1) >> 1);
            int cnt = 0;
            #pragma unroll
            for (int i = 0; i < SNI; ++i) cnt += (ul[i] >= mid) ? 1 : 0;
            #pragma unroll
            for (int o = 32; o > 0; o >>= 1) cnt += __shfl_down(cnt, o, 64);
            if (lane == 0) s_ri[w] = cnt;
            __syncthreads();
            if (tid == 0) {
                int r = 0;
                #pragma unroll
                for (int q = 0; q < 16; ++q) r += s_ri[q];
                s_i0 = r;
            }
            __syncthreads();
            if (s_i0 >= k) lo = mid; else hi = mid - 1;
        }
        float fT = __uint_as_float(lo);
        float s = 0.f; int c = 0;
        #pragma unroll
        for (int i = 0; i < SNI; ++i)
            if (ul[i] > lo) { s += __uint_as_float(ul[i]); c++; }
        #pragma unroll
        for (int o = 32; o > 0; o >>= 1) {
            s += __shfl_down(s, o, 64);
            c += __shfl_down(c, o, 64);
        }
        if (lane == 0) { s_rf[w] = s; s_ri[w] = c; }
        __syncthreads();
        if (tid == 0) {
            float ts = 0.f; int tc = 0;
            #pragma unroll
            for (int q = 0; q < 16; ++q) { ts += s_rf[q]; tc += s_ri[q]; }
            topk = ts + (float)(k - tc) * fT;
        }
    }
    if (tid == 0) {
        float* pp = part2 + b * 8;
        pp[0] = t_ll; pp[1] = t_lm; pp[2] = t_lcp;
        pp[3] = topk; pp[4] = t_np; pp[5] = t_np1;
    }
}

__global__ void k_final(const float* __restrict__ part2, float* __restrict__ out, int B) {
    int lane = threadIdx.x;
    float ll = 0, lm = 0, lcp = 0, tk = 0, np = 0, np1 = 0;
    for (int b = lane; b < B; b += 64) {
        const float* pp = part2 + b * 8;
        ll += pp[0]; lm += pp[1]; lcp += pp[2];
        tk += pp[3]; np += pp[4]; np1 += pp[5];
    }
    #pragma unroll
    for (int o = 32; o > 0; o >>= 1) {
        ll  += __shfl_down(ll, o, 64);
        lm  += __shfl_down(lm, o, 64);
        lcp += __shfl_down(lcp, o, 64);
        tk  += __shfl_down(tk, o, 64);
        np  += __shfl_down(np, o, 64);
        np1 += __shfl_down(np1, o, 64);
    }
    if (lane == 0) {
        float N = fmaxf(np, 1.f), N1 = fmaxf(np1, 1.f);
        out[0] = ll / N;
        out[1] = (lcp + tk) / N;
        out[2] = lm / N1;
    }
}

extern "C" void kernel_launch(void* const* d_in, const int* in_sizes, int n_in,
                              void* d_out, int out_size, void* d_ws, size_t ws_size,
                              hipStream_t stream) {
    const float2* cls    = (const float2*)d_in[0];
    const float4* loc    = (const float4*)d_in[1];
    const float* lmd     = (const float*)d_in[2];
    const float4* priors = (const float4*)d_in[3];
    const float* targets = (const float*)d_in[4];
    int P = in_sizes[3] / 4;          // 16800
    int B = (in_sizes[1] / 4) / P;    // 64
    int NB = (P + 255) / 256;         // 66
    int G = in_sizes[4] / (15 * B);   // 32

    size_t off = 0;
    unsigned long long* keys = (unsigned long long*)d_ws; off += (size_t)B * G * 8;
    float* part  = (float*)((char*)d_ws + off); off += (size_t)B * NB * 8 * 4;
    float* part2 = (float*)((char*)d_ws + off); off += (size_t)B * 8 * 4;
    off = (off + 255) & ~(size_t)255;
    float* bc = (float*)((char*)d_ws + off);

    dim3 ggt((G + GPB - 1) / GPB, B);
    k_gt<<<ggt, GNT, 0, stream>>>(priors, targets, keys, P, G);
    dim3 gm(NB, B);
    k_match<<<gm, 256, 0, stream>>>(cls, loc, lmd, priors, targets, keys, bc, part, P, NB);
    k_select<<<B, SNT, 0, stream>>>(bc, part, part2, P, NB);
    k_final<<<1, 64, 0, stream>>>(part2, (float*)d_out, B);
}